// Round 1
// baseline (138.973 us; speedup 1.0000x reference)
//
#include <hip/hip_runtime.h>
#include <hip/hip_bf16.h>
#include <math.h>

typedef __attribute__((ext_vector_type(8))) short short8;
typedef __attribute__((ext_vector_type(4))) float floatx4;

#define N 4096
#define D 128
#define SPLITS 4
#define MARGIN 0.3f

// ---------------- prep: fp32 -> bf16, plus exact fp32 row squared norms ----
__global__ __launch_bounds__(256) void prep_kernel(
    const float* __restrict__ m1, const float* __restrict__ m2,
    __hip_bfloat16* __restrict__ b1, __hip_bfloat16* __restrict__ b2,
    float* __restrict__ n1, float* __restrict__ n2)
{
    int wv = (blockIdx.x << 2) + (threadIdx.x >> 6);   // global wave id 0..8191
    int lane = threadIdx.x & 63;
    const float* src; __hip_bfloat16* dst; float* nd; int row;
    if (wv < N) { src = m1; dst = b1; nd = n1; row = wv; }
    else        { src = m2; dst = b2; nd = n2; row = wv - N; }

    const float2 v = *(const float2*)(src + row * D + lane * 2);
    float s = v.x * v.x + v.y * v.y;

    __hip_bfloat162 h;
    h.x = __float2bfloat16(v.x);
    h.y = __float2bfloat16(v.y);
    *(__hip_bfloat162*)(dst + row * D + lane * 2) = h;

#pragma unroll
    for (int off = 32; off > 0; off >>= 1) s += __shfl_xor(s, off, 64);
    if (lane == 0) nd[row] = s;
}

// ---------------- main: fused distance + hardest-pos/neg mining -------------
// pairs: 0:(m1,m1) 1:(m2,m2) 2:(m1,m2) 3:(m2,m1)
// Each wave owns 32 rows (two 16-row MFMA tiles); A fragments live in
// registers for the entire column sweep. Streams 16-column tiles over its
// split; running max/min on squared distance (sqrt deferred to finalize —
// both are monotone so they commute with max/min/clamp).
__global__ __launch_bounds__(256) void pair_kernel(
    const __hip_bfloat16* __restrict__ b1, const __hip_bfloat16* __restrict__ b2,
    const float* __restrict__ n1, const float* __restrict__ n2,
    const int* __restrict__ tgt,
    float* __restrict__ ap_out, float* __restrict__ an_out)
{
    const int pair   = blockIdx.z;
    const int split  = blockIdx.y;
    const int rowBlk = blockIdx.x;

    const __hip_bfloat16* A; const __hip_bfloat16* B;
    const float* nA; const float* nB;
    if (pair == 0)      { A = b1; B = b1; nA = n1; nB = n1; }
    else if (pair == 1) { A = b2; B = b2; nA = n2; nB = n2; }
    else if (pair == 2) { A = b1; B = b2; nA = n1; nB = n2; }
    else                { A = b2; B = b1; nA = n2; nB = n1; }

    const int tid  = threadIdx.x;
    const int wave = tid >> 6;
    const int lane = tid & 63;
    const int l16  = lane & 15;
    const int quad = lane >> 4;

    const int rowBase = rowBlk * 128 + wave * 32;

    // A fragments: lane holds A[row=rowBase+t*16+l16][k=c*32+quad*8 .. +7]
    short8 afrag[2][4];
#pragma unroll
    for (int t = 0; t < 2; ++t)
#pragma unroll
        for (int c = 0; c < 4; ++c)
            afrag[t][c] = *(const short8*)((const short*)A +
                              (rowBase + t * 16 + l16) * D + c * 32 + quad * 8);

    // per-lane output rows (C/D layout: col=lane&15, row=quad*4+reg)
    float nAr[2][4]; int tAr[2][4];
#pragma unroll
    for (int t = 0; t < 2; ++t)
#pragma unroll
        for (int r = 0; r < 4; ++r) {
            int row = rowBase + t * 16 + quad * 4 + r;
            nAr[t][r] = nA[row];
            tAr[t][r] = tgt[row];
        }

    float apv[2][4], anv[2][4];
#pragma unroll
    for (int t = 0; t < 2; ++t)
#pragma unroll
        for (int r = 0; r < 4; ++r) { apv[t][r] = -INFINITY; anv[t][r] = INFINITY; }

    const int colBase0 = split * (N / SPLITS);
    const int NT = (N / SPLITS) / 16;   // 64 col-tiles per split

    short8 bcur[4]; float nBc; int tBc;
    {
        int col = colBase0 + l16;
#pragma unroll
        for (int c = 0; c < 4; ++c)
            bcur[c] = *(const short8*)((const short*)B + col * D + c * 32 + quad * 8);
        nBc = nB[col]; tBc = tgt[col];
    }

    for (int ct = 0; ct < NT; ++ct) {
        // software prefetch of next tile's B fragments (wraps on last iter)
        short8 bnext[4]; float nBn; int tBn;
        {
            int ctn = (ct + 1 == NT) ? 0 : ct + 1;
            int col = colBase0 + ctn * 16 + l16;
#pragma unroll
            for (int c = 0; c < 4; ++c)
                bnext[c] = *(const short8*)((const short*)B + col * D + c * 32 + quad * 8);
            nBn = nB[col]; tBn = tgt[col];
        }

#pragma unroll
        for (int t = 0; t < 2; ++t) {
            floatx4 acc = {0.f, 0.f, 0.f, 0.f};
#pragma unroll
            for (int c = 0; c < 4; ++c)
                acc = __builtin_amdgcn_mfma_f32_16x16x32_bf16(afrag[t][c], bcur[c], acc, 0, 0, 0);
#pragma unroll
            for (int r = 0; r < 4; ++r) {
                float d2 = fmaf(acc[r], -2.f, nAr[t][r] + nBc);
                bool same = (tAr[t][r] == tBc);
                apv[t][r] = same ? fmaxf(apv[t][r], d2) : apv[t][r];
                anv[t][r] = same ? anv[t][r] : fminf(anv[t][r], d2);
            }
        }

#pragma unroll
        for (int c = 0; c < 4; ++c) bcur[c] = bnext[c];
        nBc = nBn; tBc = tBn;
    }

    // reduce across the 16 column-lanes of each quad group
#pragma unroll
    for (int t = 0; t < 2; ++t)
#pragma unroll
        for (int r = 0; r < 4; ++r) {
            float ap = apv[t][r], an = anv[t][r];
#pragma unroll
            for (int off = 1; off < 16; off <<= 1) {
                ap = fmaxf(ap, __shfl_xor(ap, off, 16));
                an = fminf(an, __shfl_xor(an, off, 16));
            }
            if (l16 == 0) {
                int row = rowBase + t * 16 + quad * 4 + r;
                int idx = (pair * SPLITS + split) * N + row;
                ap_out[idx] = ap;
                an_out[idx] = an;
            }
        }
}

// ---------------- finalize: merge splits, sqrt, loss + precision ------------
__global__ __launch_bounds__(1024) void finalize_kernel(
    const float* __restrict__ ap, const float* __restrict__ an,
    float* __restrict__ out)
{
    const int tid = threadIdx.x;
    float lsum = 0.f, psum = 0.f;
    for (int i = tid; i < 6 * N; i += 1024) {
        int list = i >> 12;          // /4096
        int r = i & (N - 1);
        int pp = (list < 4) ? list : (list - 2);   // ap pairs: 0,1,2,3,2,3
        int np = (list < 4) ? list : (list - 4);   // an pairs: 0,1,2,3,0,1
        float apv = -INFINITY, anv = INFINITY;
#pragma unroll
        for (int s = 0; s < SPLITS; ++s) {
            apv = fmaxf(apv, ap[(pp * SPLITS + s) * N + r]);
            anv = fminf(anv, an[(np * SPLITS + s) * N + r]);
        }
        float apd = sqrtf(fmaxf(apv, 1e-12f));
        float and_ = sqrtf(fmaxf(anv, 1e-12f));
        lsum += fmaxf(apd - and_ + MARGIN, 0.f);
        psum += (and_ > apd) ? 1.f : 0.f;
    }

#pragma unroll
    for (int off = 32; off > 0; off >>= 1) {
        lsum += __shfl_xor(lsum, off, 64);
        psum += __shfl_xor(psum, off, 64);
    }
    __shared__ float sl[16], sp[16];
    int w = tid >> 6;
    if ((tid & 63) == 0) { sl[w] = lsum; sp[w] = psum; }
    __syncthreads();
    if (tid == 0) {
        float L = 0.f, P = 0.f;
#pragma unroll
        for (int k = 0; k < 16; ++k) { L += sl[k]; P += sp[k]; }
        out[0] = L / (6.f * N);
        out[1] = P / (6.f * N);
    }
}

extern "C" void kernel_launch(void* const* d_in, const int* in_sizes, int n_in,
                              void* d_out, int out_size, void* d_ws, size_t ws_size,
                              hipStream_t stream)
{
    const float* m1 = (const float*)d_in[0];
    const float* m2 = (const float*)d_in[1];
    const int* tgt  = (const int*)d_in[2];
    float* out = (float*)d_out;

    char* ws = (char*)d_ws;
    __hip_bfloat16* b1 = (__hip_bfloat16*)ws;                       // 1 MB
    __hip_bfloat16* b2 = (__hip_bfloat16*)(ws + 1048576);           // 1 MB
    float* n1 = (float*)(ws + 2097152);                             // 16 KB
    float* n2 = (float*)(ws + 2097152 + 16384);                     // 16 KB
    float* ap = (float*)(ws + 2129920);                             // 256 KB
    float* an = (float*)(ws + 2129920 + 262144);                    // 256 KB

    prep_kernel<<<2048, 256, 0, stream>>>(m1, m2, b1, b2, n1, n2);
    pair_kernel<<<dim3(32, SPLITS, 4), 256, 0, stream>>>(b1, b2, n1, n2, tgt, ap, an);
    finalize_kernel<<<1, 1024, 0, stream>>>(ap, an, out);
}

// Round 2
// 130.305 us; speedup vs baseline: 1.0665x; 1.0665x over previous
//
#include <hip/hip_runtime.h>
#include <hip/hip_bf16.h>
#include <math.h>

typedef __attribute__((ext_vector_type(8))) short short8;
typedef __attribute__((ext_vector_type(4))) float floatx4;

#define N 4096
#define D 128
#define SPLITS 8
#define MARGIN 0.3f

// ---------------- prep: fp32 -> bf16, exact fp32 row squared norms ---------
// 2 rows per wave (float4 per lane), 8 rows per 256-thr block -> 1024 blocks.
// Also zero-inits d_out (finalize accumulates into it with atomics).
__global__ __launch_bounds__(256) void prep_kernel(
    const float* __restrict__ m1, const float* __restrict__ m2,
    __hip_bfloat16* __restrict__ b1, __hip_bfloat16* __restrict__ b2,
    float* __restrict__ n1, float* __restrict__ n2,
    float* __restrict__ out)
{
    if (blockIdx.x == 0 && threadIdx.x == 0) { out[0] = 0.f; out[1] = 0.f; }

    int wv   = blockIdx.x * 4 + (threadIdx.x >> 6);   // 0..4095 (2 rows each)
    int lane = threadIdx.x & 63;
    int half = lane >> 5;                             // 0/1: which row of the pair
    int l32  = lane & 31;

    int g = wv * 2 + half;                            // global row 0..8191
    const float* src; __hip_bfloat16* dst; float* nd; int row;
    if (g < N) { src = m1; dst = b1; nd = n1; row = g; }
    else       { src = m2; dst = b2; nd = n2; row = g - N; }

    float4 v = *(const float4*)(src + row * D + l32 * 4);
    float s = v.x * v.x + v.y * v.y + v.z * v.z + v.w * v.w;

    __hip_bfloat16 h0 = __float2bfloat16(v.x), h1 = __float2bfloat16(v.y);
    __hip_bfloat16 h2 = __float2bfloat16(v.z), h3 = __float2bfloat16(v.w);
    short4 pk;
    pk.x = *(short*)&h0; pk.y = *(short*)&h1; pk.z = *(short*)&h2; pk.w = *(short*)&h3;
    *(short4*)((short*)dst + row * D + l32 * 4) = pk;

    // reduce within each 32-lane half (xor offsets <32 stay inside the half)
#pragma unroll
    for (int off = 16; off > 0; off >>= 1) s += __shfl_xor(s, off, 64);
    if (l32 == 0) nd[row] = s;
}

// ---------------- main: fused distance + hardest-pos/neg mining -------------
// pairs: 0:(m1,m1) 1:(m2,m2) 2:(m1,m2) 3:(m2,m1)
// Wave owns 32 rows; A fragments pinned in registers. Streams 16-col tiles
// over its 512-col split with prefetch. Mines on (nB - 2*A.B) per squared
// distance; the per-row norm nA is a constant across the reduced axis, so it
// is added after the 16-lane reduction (max/min commute with +const).
__global__ __launch_bounds__(256) void pair_kernel(
    const __hip_bfloat16* __restrict__ b1, const __hip_bfloat16* __restrict__ b2,
    const float* __restrict__ n1, const float* __restrict__ n2,
    const int* __restrict__ tgt,
    float* __restrict__ ap_out, float* __restrict__ an_out)
{
    const int pair   = blockIdx.z;
    const int split  = blockIdx.y;
    const int rowBlk = blockIdx.x;

    const __hip_bfloat16* A; const __hip_bfloat16* B;
    const float* nA; const float* nB;
    if (pair == 0)      { A = b1; B = b1; nA = n1; nB = n1; }
    else if (pair == 1) { A = b2; B = b2; nA = n2; nB = n2; }
    else if (pair == 2) { A = b1; B = b2; nA = n1; nB = n2; }
    else                { A = b2; B = b1; nA = n2; nB = n1; }

    const int tid  = threadIdx.x;
    const int wave = tid >> 6;
    const int lane = tid & 63;
    const int l16  = lane & 15;
    const int quad = lane >> 4;

    const int rowBase = rowBlk * 128 + wave * 32;

    // A fragments: lane holds A[row=rowBase+t*16+l16][k=c*32+quad*8 .. +7]
    short8 afrag[2][4];
#pragma unroll
    for (int t = 0; t < 2; ++t)
#pragma unroll
        for (int c = 0; c < 4; ++c)
            afrag[t][c] = *(const short8*)((const short*)A +
                              (rowBase + t * 16 + l16) * D + c * 32 + quad * 8);

    // per-lane output rows (C/D layout: col=lane&15, row=quad*4+reg)
    float nAr[2][4]; int tAr[2][4];
#pragma unroll
    for (int t = 0; t < 2; ++t)
#pragma unroll
        for (int r = 0; r < 4; ++r) {
            int row = rowBase + t * 16 + quad * 4 + r;
            nAr[t][r] = nA[row];
            tAr[t][r] = tgt[row];
        }

    float apv[2][4], anv[2][4];
#pragma unroll
    for (int t = 0; t < 2; ++t)
#pragma unroll
        for (int r = 0; r < 4; ++r) { apv[t][r] = -INFINITY; anv[t][r] = INFINITY; }

    const int colBase0 = split * (N / SPLITS);
    const int NT = (N / SPLITS) / 16;   // 32 col-tiles per split

    short8 bcur[4]; float nBc; int tBc;
    {
        int col = colBase0 + l16;
#pragma unroll
        for (int c = 0; c < 4; ++c)
            bcur[c] = *(const short8*)((const short*)B + col * D + c * 32 + quad * 8);
        nBc = nB[col]; tBc = tgt[col];
    }

    for (int ct = 0; ct < NT; ++ct) {
        // software prefetch of next tile's B fragments (wraps on last iter)
        short8 bnext[4]; float nBn; int tBn;
        {
            int ctn = (ct + 1 == NT) ? 0 : ct + 1;
            int col = colBase0 + ctn * 16 + l16;
#pragma unroll
            for (int c = 0; c < 4; ++c)
                bnext[c] = *(const short8*)((const short*)B + col * D + c * 32 + quad * 8);
            nBn = nB[col]; tBn = tgt[col];
        }

#pragma unroll
        for (int t = 0; t < 2; ++t) {
            floatx4 acc = {0.f, 0.f, 0.f, 0.f};
#pragma unroll
            for (int c = 0; c < 4; ++c)
                acc = __builtin_amdgcn_mfma_f32_16x16x32_bf16(afrag[t][c], bcur[c], acc, 0, 0, 0);
#pragma unroll
            for (int r = 0; r < 4; ++r) {
                float d2 = fmaf(acc[r], -2.f, nBc);          // nA deferred
                bool same = (tAr[t][r] == tBc);
                apv[t][r] = fmaxf(apv[t][r], same ? d2 : -INFINITY);
                anv[t][r] = fminf(anv[t][r], same ? INFINITY : d2);
            }
        }

#pragma unroll
        for (int c = 0; c < 4; ++c) bcur[c] = bnext[c];
        nBc = nBn; tBc = tBn;
    }

    // reduce across the 16 column-lanes; then add the deferred row norm
#pragma unroll
    for (int t = 0; t < 2; ++t)
#pragma unroll
        for (int r = 0; r < 4; ++r) {
            float ap = apv[t][r], an = anv[t][r];
#pragma unroll
            for (int off = 1; off < 16; off <<= 1) {
                ap = fmaxf(ap, __shfl_xor(ap, off, 16));
                an = fminf(an, __shfl_xor(an, off, 16));
            }
            if (l16 == 0) {
                int row = rowBase + t * 16 + quad * 4 + r;
                int idx = (pair * SPLITS + split) * N + row;
                ap_out[idx] = ap + nAr[t][r];
                an_out[idx] = an + nAr[t][r];
            }
        }
}

// ---------------- finalize: merge splits, sqrt, loss + precision ------------
// one thread per (list,row); block partial sums -> atomicAdd into d_out
__global__ __launch_bounds__(256) void finalize_kernel(
    const float* __restrict__ ap, const float* __restrict__ an,
    float* __restrict__ out)
{
    const int idx = blockIdx.x * 256 + threadIdx.x;     // 0..24575
    const int list = idx >> 12;
    const int r = idx & (N - 1);
    const int pp = (list < 4) ? list : (list - 2);      // ap pairs: 0,1,2,3,2,3
    const int np = (list < 4) ? list : (list - 4);      // an pairs: 0,1,2,3,0,1

    float apv = -INFINITY, anv = INFINITY;
#pragma unroll
    for (int s = 0; s < SPLITS; ++s) {
        apv = fmaxf(apv, ap[(pp * SPLITS + s) * N + r]);
        anv = fminf(anv, an[(np * SPLITS + s) * N + r]);
    }
    float apd = sqrtf(fmaxf(apv, 1e-12f));
    float and_ = sqrtf(fmaxf(anv, 1e-12f));
    float lsum = fmaxf(apd - and_ + MARGIN, 0.f);
    float psum = (and_ > apd) ? 1.f : 0.f;

#pragma unroll
    for (int off = 32; off > 0; off >>= 1) {
        lsum += __shfl_xor(lsum, off, 64);
        psum += __shfl_xor(psum, off, 64);
    }
    __shared__ float sl[4], sp[4];
    int w = threadIdx.x >> 6;
    if ((threadIdx.x & 63) == 0) { sl[w] = lsum; sp[w] = psum; }
    __syncthreads();
    if (threadIdx.x == 0) {
        float L = sl[0] + sl[1] + sl[2] + sl[3];
        float P = sp[0] + sp[1] + sp[2] + sp[3];
        const float inv = 1.f / (6.f * N);
        atomicAdd(&out[0], L * inv);
        atomicAdd(&out[1], P * inv);
    }
}

extern "C" void kernel_launch(void* const* d_in, const int* in_sizes, int n_in,
                              void* d_out, int out_size, void* d_ws, size_t ws_size,
                              hipStream_t stream)
{
    const float* m1 = (const float*)d_in[0];
    const float* m2 = (const float*)d_in[1];
    const int* tgt  = (const int*)d_in[2];
    float* out = (float*)d_out;

    char* ws = (char*)d_ws;
    __hip_bfloat16* b1 = (__hip_bfloat16*)ws;                       // 1 MB
    __hip_bfloat16* b2 = (__hip_bfloat16*)(ws + 1048576);           // 1 MB
    float* n1 = (float*)(ws + 2097152);                             // 16 KB
    float* n2 = (float*)(ws + 2097152 + 16384);                     // 16 KB
    float* ap = (float*)(ws + 2129920);                             // 512 KB (4*8*4096*4B)
    float* an = (float*)(ws + 2129920 + 524288);                    // 512 KB

    prep_kernel<<<1024, 256, 0, stream>>>(m1, m2, b1, b2, n1, n2, out);
    pair_kernel<<<dim3(32, SPLITS, 4), 256, 0, stream>>>(b1, b2, n1, n2, tgt, ap, an);
    finalize_kernel<<<96, 256, 0, stream>>>(ap, an, out);
}

// Round 3
// 91.249 us; speedup vs baseline: 1.5230x; 1.4280x over previous
//
#include <hip/hip_runtime.h>
#include <hip/hip_bf16.h>
#include <math.h>

typedef __attribute__((ext_vector_type(8))) short short8;
typedef __attribute__((ext_vector_type(4))) float floatx4;

#define N 4096
#define D 128
#define SPLITS 8
#define MARGIN 0.3f

#define GLOBAL_LOAD_LDS16(g, l) \
    __builtin_amdgcn_global_load_lds((const __attribute__((address_space(1))) void*)(g), \
                                     (__attribute__((address_space(3))) void*)(l), 16, 0, 0)

// ---------------- prep: fp32 -> bf16, exact fp32 row squared norms ---------
__global__ __launch_bounds__(256) void prep_kernel(
    const float* __restrict__ m1, const float* __restrict__ m2,
    __hip_bfloat16* __restrict__ b1, __hip_bfloat16* __restrict__ b2,
    float* __restrict__ n1, float* __restrict__ n2,
    float* __restrict__ out)
{
    if (blockIdx.x == 0 && threadIdx.x == 0) { out[0] = 0.f; out[1] = 0.f; }

    int wv   = blockIdx.x * 4 + (threadIdx.x >> 6);   // 0..4095 (2 rows each)
    int lane = threadIdx.x & 63;
    int half = lane >> 5;
    int l32  = lane & 31;

    int g = wv * 2 + half;                            // global row 0..8191
    const float* src; __hip_bfloat16* dst; float* nd; int row;
    if (g < N) { src = m1; dst = b1; nd = n1; row = g; }
    else       { src = m2; dst = b2; nd = n2; row = g - N; }

    float4 v = *(const float4*)(src + row * D + l32 * 4);
    float s = v.x * v.x + v.y * v.y + v.z * v.z + v.w * v.w;

    __hip_bfloat16 h0 = __float2bfloat16(v.x), h1 = __float2bfloat16(v.y);
    __hip_bfloat16 h2 = __float2bfloat16(v.z), h3 = __float2bfloat16(v.w);
    short4 pk;
    pk.x = *(short*)&h0; pk.y = *(short*)&h1; pk.z = *(short*)&h2; pk.w = *(short*)&h3;
    *(short4*)((short*)dst + row * D + l32 * 4) = pk;

#pragma unroll
    for (int off = 16; off > 0; off >>= 1) s += __shfl_xor(s, off, 64);
    if (l32 == 0) nd[row] = s;
}

// ---------------- main: LDS-staged fused distance + hardest mining ----------
// m97-style: double-buffered LDS B-tiles (32 cols x 128 k bf16 = 8 KB each),
// staged with global_load_lds width=16 and shared by all 4 waves of the block.
// LDS layout XOR-swizzled: B[col][k-chunk j] lives at slot (j ^ (col&15)) so
// the 256 B column stride doesn't cause ds_read_b128 bank conflicts (2-way
// max = free). Mining runs on (nB - 2*dot); row norm nA added post-reduction.
__global__ __launch_bounds__(256, 4) void pair_kernel(
    const __hip_bfloat16* __restrict__ b1, const __hip_bfloat16* __restrict__ b2,
    const float* __restrict__ n1, const float* __restrict__ n2,
    const int* __restrict__ tgt,
    float* __restrict__ ap_out, float* __restrict__ an_out)
{
    const int pair   = blockIdx.z;
    const int split  = blockIdx.y;
    const int rowBlk = blockIdx.x;

    const __hip_bfloat16* A; const __hip_bfloat16* B;
    const float* nA; const float* nB;
    if (pair == 0)      { A = b1; B = b1; nA = n1; nB = n1; }
    else if (pair == 1) { A = b2; B = b2; nA = n2; nB = n2; }
    else if (pair == 2) { A = b1; B = b2; nA = n1; nB = n2; }
    else                { A = b2; B = b1; nA = n2; nB = n1; }

    __shared__ char ldsbuf[16384];                     // 2 x 8 KB

    const int tid  = threadIdx.x;
    const int wave = tid >> 6;
    const int lane = tid & 63;
    const int l16  = lane & 15;
    const int quad = lane >> 4;

    const int rowBase = rowBlk * 128 + wave * 32;

    // A fragments pinned for the whole sweep:
    // lane holds A[row=rowBase+t*16+l16][k=c*32+quad*8 .. +7]
    short8 afrag[2][4];
#pragma unroll
    for (int t = 0; t < 2; ++t)
#pragma unroll
        for (int c = 0; c < 4; ++c)
            afrag[t][c] = *(const short8*)((const short*)A +
                              (rowBase + t * 16 + l16) * D + c * 32 + quad * 8);

    // per-lane output rows (C/D layout: col=lane&15, row=quad*4+reg)
    float nAr[2][4]; int tAr[2][4];
#pragma unroll
    for (int t = 0; t < 2; ++t)
#pragma unroll
        for (int r = 0; r < 4; ++r) {
            int row = rowBase + t * 16 + quad * 4 + r;
            nAr[t][r] = nA[row];
            tAr[t][r] = tgt[row];
        }

    float apv[2][4], anv[2][4];
#pragma unroll
    for (int t = 0; t < 2; ++t)
#pragma unroll
        for (int r = 0; r < 4; ++r) { apv[t][r] = -INFINITY; anv[t][r] = INFINITY; }

    // staging geometry: per round r (0,1), thread covers LDS bytes
    // o = r*4096 + wave*1024 + lane*16  ->  col=o>>8, slot=(o>>4)&15,
    // source chunk j = slot ^ (col&15)
    int srcRel[2], dstRel[2];
#pragma unroll
    for (int r = 0; r < 2; ++r) {
        int o    = r * 4096 + wave * 1024 + lane * 16;
        int col  = o >> 8;
        int slot = (o >> 4) & 15;
        int j    = slot ^ (col & 15);
        srcRel[r] = col * 256 + j * 16;   // bytes within the 32-col tile
        dstRel[r] = o;
    }
    // ds_read lane offsets: chunk (c*4+quad) of col l16 -> slot ^(l16)
    int roff[4];
#pragma unroll
    for (int c = 0; c < 4; ++c)
        roff[c] = l16 * 256 + (((c * 4 + quad) ^ l16) << 4);

    const int colBase = split * (N / SPLITS);          // 512-col split
    const int NT = (N / SPLITS) / 32;                  // 16 iters of 32 cols
    const char* Bbytes = (const char*)B;

    // prologue: stage tile 0 into buf 0
#pragma unroll
    for (int r = 0; r < 2; ++r)
        GLOBAL_LOAD_LDS16(Bbytes + (size_t)colBase * 256 + srcRel[r],
                          ldsbuf + dstRel[r]);
    __syncthreads();

    for (int it = 0; it < NT; it += 2) {
#pragma unroll
        for (int h = 0; h < 2; ++h) {
            const int i = it + h;                      // buffer h (compile-time)
            if (i + 1 < NT) {                          // stage next into buf h^1
                const char* src = Bbytes + (size_t)(colBase + (i + 1) * 32) * 256;
#pragma unroll
                for (int r = 0; r < 2; ++r)
                    GLOBAL_LOAD_LDS16(src + srcRel[r],
                                      ldsbuf + ((h ^ 1) * 8192) + dstRel[r]);
            }
#pragma unroll
            for (int ct2 = 0; ct2 < 2; ++ct2) {
                int col = colBase + i * 32 + ct2 * 16 + l16;
                float nBc = nB[col];
                int   tBc = tgt[col];
                short8 bf[4];
#pragma unroll
                for (int c = 0; c < 4; ++c)
                    bf[c] = *(const short8*)(ldsbuf + h * 8192 + ct2 * 4096 + roff[c]);
#pragma unroll
                for (int t = 0; t < 2; ++t) {
                    floatx4 acc = {0.f, 0.f, 0.f, 0.f};
#pragma unroll
                    for (int c = 0; c < 4; ++c)
                        acc = __builtin_amdgcn_mfma_f32_16x16x32_bf16(afrag[t][c], bf[c], acc, 0, 0, 0);
#pragma unroll
                    for (int r = 0; r < 4; ++r) {
                        float d2 = fmaf(acc[r], -2.f, nBc);   // nA deferred
                        bool same = (tAr[t][r] == tBc);
                        apv[t][r] = fmaxf(apv[t][r], same ? d2 : -INFINITY);
                        anv[t][r] = fminf(anv[t][r], same ? INFINITY : d2);
                    }
                }
            }
            __syncthreads();   // drains global_load_lds (next buf ready) +
                               // all waves done reading buf h
        }
    }

    // reduce across the 16 column-lanes; add deferred row norm
#pragma unroll
    for (int t = 0; t < 2; ++t)
#pragma unroll
        for (int r = 0; r < 4; ++r) {
            float ap = apv[t][r], an = anv[t][r];
#pragma unroll
            for (int off = 1; off < 16; off <<= 1) {
                ap = fmaxf(ap, __shfl_xor(ap, off, 16));
                an = fminf(an, __shfl_xor(an, off, 16));
            }
            if (l16 == 0) {
                int row = rowBase + t * 16 + quad * 4 + r;
                int idx = (pair * SPLITS + split) * N + row;
                ap_out[idx] = ap + nAr[t][r];
                an_out[idx] = an + nAr[t][r];
            }
        }
}

// ---------------- finalize: merge splits, sqrt, loss + precision ------------
__global__ __launch_bounds__(256) void finalize_kernel(
    const float* __restrict__ ap, const float* __restrict__ an,
    float* __restrict__ out)
{
    const int idx = blockIdx.x * 256 + threadIdx.x;     // 0..24575
    const int list = idx >> 12;
    const int r = idx & (N - 1);
    const int pp = (list < 4) ? list : (list - 2);      // ap pairs: 0,1,2,3,2,3
    const int np = (list < 4) ? list : (list - 4);      // an pairs: 0,1,2,3,0,1

    float apv = -INFINITY, anv = INFINITY;
#pragma unroll
    for (int s = 0; s < SPLITS; ++s) {
        apv = fmaxf(apv, ap[(pp * SPLITS + s) * N + r]);
        anv = fminf(anv, an[(np * SPLITS + s) * N + r]);
    }
    float apd = sqrtf(fmaxf(apv, 1e-12f));
    float and_ = sqrtf(fmaxf(anv, 1e-12f));
    float lsum = fmaxf(apd - and_ + MARGIN, 0.f);
    float psum = (and_ > apd) ? 1.f : 0.f;

#pragma unroll
    for (int off = 32; off > 0; off >>= 1) {
        lsum += __shfl_xor(lsum, off, 64);
        psum += __shfl_xor(psum, off, 64);
    }
    __shared__ float sl[4], sp[4];
    int w = threadIdx.x >> 6;
    if ((threadIdx.x & 63) == 0) { sl[w] = lsum; sp[w] = psum; }
    __syncthreads();
    if (threadIdx.x == 0) {
        float L = sl[0] + sl[1] + sl[2] + sl[3];
        float P = sp[0] + sp[1] + sp[2] + sp[3];
        const float inv = 1.f / (6.f * N);
        atomicAdd(&out[0], L * inv);
        atomicAdd(&out[1], P * inv);
    }
}

extern "C" void kernel_launch(void* const* d_in, const int* in_sizes, int n_in,
                              void* d_out, int out_size, void* d_ws, size_t ws_size,
                              hipStream_t stream)
{
    const float* m1 = (const float*)d_in[0];
    const float* m2 = (const float*)d_in[1];
    const int* tgt  = (const int*)d_in[2];
    float* out = (float*)d_out;

    char* ws = (char*)d_ws;
    __hip_bfloat16* b1 = (__hip_bfloat16*)ws;                       // 1 MB
    __hip_bfloat16* b2 = (__hip_bfloat16*)(ws + 1048576);           // 1 MB
    float* n1 = (float*)(ws + 2097152);                             // 16 KB
    float* n2 = (float*)(ws + 2097152 + 16384);                     // 16 KB
    float* ap = (float*)(ws + 2129920);                             // 512 KB (4*8*4096*4B)
    float* an = (float*)(ws + 2129920 + 524288);                    // 512 KB

    prep_kernel<<<1024, 256, 0, stream>>>(m1, m2, b1, b2, n1, n2, out);
    pair_kernel<<<dim3(32, SPLITS, 4), 256, 0, stream>>>(b1, b2, n1, n2, tgt, ap, an);
    finalize_kernel<<<96, 256, 0, stream>>>(ap, an, out);
}